// Round 3
// baseline (2375.080 us; speedup 1.0000x reference)
//
#include <hip/hip_runtime.h>
#include <float.h>
#include <math.h>

#define Bg   8
#define NPGc 6250
#define Hh   4
#define Dd   128
#define Nn   50000
#define Ee   400000
#define HDd  512

__device__ __forceinline__ void atomicMaxF(float* addr, float val) {
    // ordered-int trick: works for mixed signs given IEEE-754 ordering
    if (val >= 0.0f) atomicMax((int*)addr, __float_as_int(val));
    else             atomicMin((unsigned int*)addr, __float_as_uint(val));
}

__global__ void init_kernel(float* m, float* denom, float* dout, float* din, float* pools) {
    int i = blockIdx.x * blockDim.x + threadIdx.x;
    if (i < Nn * Hh) { m[i] = -FLT_MAX; denom[i] = 0.0f; }
    if (i < Nn)      { dout[i] = 0.0f; din[i] = 0.0f; }
    if (i < Bg * 3 * Dd) pools[i] = -FLT_MAX;
}

__global__ void gather_kernel(const int* __restrict__ ids, const float* __restrict__ emb,
                              float* __restrict__ feat) {
    int i = blockIdx.x * blockDim.x + threadIdx.x;  // over N*32 float4s
    int n = i >> 5, c = i & 31;
    int id = ids[n];
    ((float4*)feat)[(size_t)n * 32 + c] = ((const float4*)emb)[(size_t)id * 32 + c];
}

// per-graph max over nodes for a [N,128] feature; blocks = (B, 50), 125 rows each
__global__ void maxpool_kernel(const float* __restrict__ x, float* __restrict__ pools, int col_off) {
    int b = blockIdx.x, chunk = blockIdx.y, d = threadIdx.x;
    int i0 = chunk * 125, i1 = i0 + 125;
    float mx = -FLT_MAX;
    for (int i = i0; i < i1; ++i)
        mx = fmaxf(mx, x[((size_t)(b * NPGc + i)) * Dd + d]);
    atomicMaxF(&pools[b * (3 * Dd) + col_off + d], mx);
}

// C[n,c] = leaky?( sum_k A[n,k]*scale(n) * W[k,c] + bias[c] )
// A:[n_rows,128], W:[128,WN], tile 64x64, 256 thr, 4x4 reg tile
__global__ __launch_bounds__(256) void gemm_kernel(
    const float* __restrict__ A, const float* __restrict__ W,
    const float* __restrict__ bias, float* __restrict__ C,
    int n_rows, int WN, const float* __restrict__ rowscale,
    int do_leak, float leak)
{
    __shared__ float As[64 * 132];   // padded stride 132
    __shared__ float Ws[64 * 64];    // one k-half at a time
    int row0 = blockIdx.x * 64;
    int col0 = blockIdx.y * 64;
    int tid  = threadIdx.x;

    // stage A tile: 64x128 = 8192 floats, 8 float4 per thread
    #pragma unroll
    for (int it = 0; it < 8; ++it) {
        int idx = (it * 256 + tid) * 4;
        int r = idx >> 7, c = idx & 127;
        int grow = row0 + r;
        float4 v = make_float4(0.f, 0.f, 0.f, 0.f);
        if (grow < n_rows) {
            v = *(const float4*)(A + (size_t)grow * 128 + c);
            if (rowscale) {
                float sc = 1.0f / sqrtf(fmaxf(rowscale[grow], 1.0f));
                v.x *= sc; v.y *= sc; v.z *= sc; v.w *= sc;
            }
        }
        *(float4*)(As + r * 132 + c) = v;
    }

    int tx = tid & 15, ty = tid >> 4;
    int r0 = ty * 4, c0 = tx * 4;
    float acc[4][4] = {};

    for (int kp = 0; kp < 2; ++kp) {
        __syncthreads();
        // stage W half: 64x64 = 4096 floats, 4 float4 per thread
        #pragma unroll
        for (int it = 0; it < 4; ++it) {
            int idx = (it * 256 + tid) * 4;
            int kk = idx >> 6, c = idx & 63;
            float4 v = *(const float4*)(W + (size_t)(kp * 64 + kk) * WN + col0 + c);
            *(float4*)(Ws + kk * 64 + c) = v;
        }
        __syncthreads();
        #pragma unroll 8
        for (int kk = 0; kk < 64; ++kk) {
            int k = kp * 64 + kk;
            float a[4];
            #pragma unroll
            for (int i = 0; i < 4; ++i) a[i] = As[(r0 + i) * 132 + k];
            float4 wv = *(const float4*)(Ws + kk * 64 + c0);
            float w[4] = {wv.x, wv.y, wv.z, wv.w};
            #pragma unroll
            for (int i = 0; i < 4; ++i)
                #pragma unroll
                for (int j = 0; j < 4; ++j)
                    acc[i][j] = fmaf(a[i], w[j], acc[i][j]);
        }
    }

    #pragma unroll
    for (int i = 0; i < 4; ++i) {
        int grow = row0 + r0 + i;
        if (grow >= n_rows) continue;
        float o[4];
        #pragma unroll
        for (int j = 0; j < 4; ++j) {
            float v = acc[i][j] + bias[col0 + c0 + j];
            if (do_leak) v = v >= 0.0f ? v : leak * v;
            o[j] = v;
        }
        *(float4*)(C + (size_t)grow * WN + col0 + c0) = *(float4*)o;
    }
}

// Pass A: one wave per edge; logits[e,h] = dot(leaky(hs[s]+hd[d],0.2), attn[h]); m = segmax
__global__ __launch_bounds__(256) void edge_logits_kernel(
    const float* __restrict__ hs, const float* __restrict__ hd,
    const int* __restrict__ src, const int* __restrict__ dst,
    const float* __restrict__ attn, float* __restrict__ logits, float* __restrict__ m)
{
    int w = (blockIdx.x * 256 + threadIdx.x) >> 6;
    int lane = threadIdx.x & 63;
    int s = src[w], d0 = dst[w];
    const float2* hsp = (const float2*)(hs + (size_t)s * HDd);
    const float2* hdp = (const float2*)(hd + (size_t)d0 * HDd);
    const float2* ap  = (const float2*)attn;
    #pragma unroll
    for (int h = 0; h < 4; ++h) {
        float2 a  = hsp[h * 64 + lane];
        float2 b  = hdp[h * 64 + lane];
        float2 at = ap[h * 64 + lane];
        float x0 = a.x + b.x; x0 = x0 >= 0.0f ? x0 : 0.2f * x0;
        float x1 = a.y + b.y; x1 = x1 >= 0.0f ? x1 : 0.2f * x1;
        float v = fmaf(x0, at.x, x1 * at.y);
        #pragma unroll
        for (int off = 32; off > 0; off >>= 1) v += __shfl_xor(v, off);
        if (lane == 0) {
            logits[(size_t)w * 4 + h] = v;
            atomicMaxF(&m[(size_t)d0 * 4 + h], v);
        }
    }
}

// Pass B: ex = exp(logit - m[dst]); denom[dst] += ex  (in-place over logits)
__global__ void edge_exp_kernel(const int* __restrict__ dst, float* __restrict__ logits,
                                const float* __restrict__ m, float* __restrict__ denom) {
    int i = blockIdx.x * blockDim.x + threadIdx.x;  // over E*4
    int e = i >> 2, h = i & 3;
    int d0 = dst[e];
    float ex = expf(logits[i] - m[(size_t)d0 * 4 + h]);
    logits[i] = ex;
    atomicAdd(&denom[(size_t)d0 * 4 + h], ex);
}

// Pass C: rst[dst] += hs[src] * alpha   (rst pre-initialized to x@W_res+b_res)
__global__ __launch_bounds__(256) void edge_aggregate_kernel(
    const float* __restrict__ hs, const float* __restrict__ ex, const float* __restrict__ denom,
    const int* __restrict__ src, const int* __restrict__ dst, float* __restrict__ rst)
{
    int w = (blockIdx.x * 256 + threadIdx.x) >> 6;
    int lane = threadIdx.x & 63;
    int s = src[w], d0 = dst[w];
    const float2* hsp = (const float2*)(hs + (size_t)s * HDd);
    float* rp = rst + (size_t)d0 * HDd;
    #pragma unroll
    for (int h = 0; h < 4; ++h) {
        float alpha = ex[(size_t)w * 4 + h] / denom[(size_t)d0 * 4 + h];
        float2 a = hsp[h * 64 + lane];
        atomicAdd(rp + h * 128 + 2 * lane,     a.x * alpha);
        atomicAdd(rp + h * 128 + 2 * lane + 1, a.y * alpha);
    }
}

// res[n,d] = mean_h leaky(rst[n,h,d], 0.01)
__global__ void head_mean_kernel(const float* __restrict__ rst, float* __restrict__ res) {
    int i = blockIdx.x * blockDim.x + threadIdx.x;  // N*128
    int n = i >> 7, d = i & 127;
    const float* r = rst + (size_t)n * HDd + d;
    float sum = 0.0f;
    #pragma unroll
    for (int h = 0; h < 4; ++h) {
        float v = r[h * 128];
        v = v >= 0.0f ? v : 0.01f * v;
        sum += v;
    }
    res[i] = 0.25f * sum;
}

__global__ void degree_kernel(const int* __restrict__ src, const int* __restrict__ dst,
                              float* __restrict__ dout, float* __restrict__ din) {
    int e = blockIdx.x * blockDim.x + threadIdx.x;
    if (e >= Ee) return;
    atomicAdd(&dout[src[e]], 1.0f);
    atomicAdd(&din[dst[e]], 1.0f);
}

// agg[dst] += res[src] * rsqrt(max(dout[src],1))
__global__ __launch_bounds__(256) void gc_agg_kernel(
    const float* __restrict__ res, const int* __restrict__ src, const int* __restrict__ dst,
    const float* __restrict__ dout, float* __restrict__ agg)
{
    int w = (blockIdx.x * 256 + threadIdx.x) >> 6;
    int lane = threadIdx.x & 63;
    int s = src[w], d0 = dst[w];
    float sc = 1.0f / sqrtf(fmaxf(dout[s], 1.0f));
    float2 a = ((const float2*)(res + (size_t)s * Dd))[lane];
    atomicAdd(agg + (size_t)d0 * Dd + 2 * lane,     a.x * sc);
    atomicAdd(agg + (size_t)d0 * Dd + 2 * lane + 1, a.y * sc);
}

// out[b] = relu(pools[b]) . W_mlp + b_mlp
__global__ void final_kernel(const float* __restrict__ pools, const float* __restrict__ W_mlp,
                             const float* __restrict__ b_mlp, float* __restrict__ out) {
    int b = blockIdx.x, lane = threadIdx.x;  // 64 threads
    float s = 0.0f;
    for (int j = lane; j < 3 * Dd; j += 64)
        s += fmaxf(pools[b * (3 * Dd) + j], 0.0f) * W_mlp[j];
    #pragma unroll
    for (int off = 32; off > 0; off >>= 1) s += __shfl_xor(s, off);
    if (lane == 0) out[b] = s + b_mlp[0];
}

extern "C" void kernel_launch(void* const* d_in, const int* in_sizes, int n_in,
                              void* d_out, int out_size, void* d_ws, size_t ws_size,
                              hipStream_t stream) {
    const int*   node_ids = (const int*)d_in[0];
    const int*   src      = (const int*)d_in[1];
    const int*   dst      = (const int*)d_in[2];
    const float* emb      = (const float*)d_in[3];
    const float* W_src    = (const float*)d_in[4];
    const float* b_src    = (const float*)d_in[5];
    const float* W_dst    = (const float*)d_in[6];
    const float* b_dst    = (const float*)d_in[7];
    const float* attn     = (const float*)d_in[8];
    const float* W_res    = (const float*)d_in[9];
    const float* b_res    = (const float*)d_in[10];
    const float* W_gc     = (const float*)d_in[11];
    const float* b_gc     = (const float*)d_in[12];
    const float* W_mlp    = (const float*)d_in[13];
    const float* b_mlp    = (const float*)d_in[14];
    float* out = (float*)d_out;

    float* ws = (float*)d_ws;
    size_t off = 0;
    float* feat   = ws + off; off += (size_t)Nn * Dd;    // reused as res later
    float* hs     = ws + off; off += (size_t)Nn * HDd;   // reused as agg + res2 later
    float* hd     = ws + off; off += (size_t)Nn * HDd;   // reused as rst later
    float* logits = ws + off; off += (size_t)Ee * Hh;    // reused as ex in-place
    float* m      = ws + off; off += (size_t)Nn * Hh;
    float* denom  = ws + off; off += (size_t)Nn * Hh;
    float* doutd  = ws + off; off += Nn;
    float* dind   = ws + off; off += Nn;
    float* pools  = ws + off; off += Bg * 3 * Dd;

    float* rst  = hd;                         // hd dead after edge_logits
    float* res  = feat;                       // feat dead after W_res GEMM
    float* agg  = hs;                         // hs dead after edge_aggregate
    float* res2 = hs + (size_t)Nn * Dd;

    init_kernel<<<(Nn * Hh + 255) / 256, 256, 0, stream>>>(m, denom, doutd, dind, pools);
    gather_kernel<<<(Nn * 32) / 256, 256, 0, stream>>>(node_ids, emb, feat);
    maxpool_kernel<<<dim3(Bg, 50), Dd, 0, stream>>>(feat, pools, 0);

    gemm_kernel<<<dim3(782, 8), 256, 0, stream>>>(feat, W_src, b_src, hs, Nn, HDd, nullptr, 0, 0.0f);
    gemm_kernel<<<dim3(782, 8), 256, 0, stream>>>(feat, W_dst, b_dst, hd, Nn, HDd, nullptr, 0, 0.0f);

    edge_logits_kernel<<<Ee / 4, 256, 0, stream>>>(hs, hd, src, dst, attn, logits, m);
    edge_exp_kernel<<<(Ee * Hh) / 256, 256, 0, stream>>>(dst, logits, m, denom);

    gemm_kernel<<<dim3(782, 8), 256, 0, stream>>>(feat, W_res, b_res, rst, Nn, HDd, nullptr, 0, 0.0f);
    edge_aggregate_kernel<<<Ee / 4, 256, 0, stream>>>(hs, logits, denom, src, dst, rst);

    head_mean_kernel<<<(Nn * Dd) / 256, 256, 0, stream>>>(rst, res);
    maxpool_kernel<<<dim3(Bg, 50), Dd, 0, stream>>>(res, pools, Dd);

    degree_kernel<<<(Ee + 255) / 256, 256, 0, stream>>>(src, dst, doutd, dind);
    hipMemsetAsync(agg, 0, (size_t)Nn * Dd * sizeof(float), stream);
    gc_agg_kernel<<<Ee / 4, 256, 0, stream>>>(res, src, dst, doutd, agg);
    gemm_kernel<<<dim3(782, 2), 256, 0, stream>>>(agg, W_gc, b_gc, res2, Nn, Dd, dind, 1, 0.01f);
    maxpool_kernel<<<dim3(Bg, 50), Dd, 0, stream>>>(res2, pools, 2 * Dd);

    final_kernel<<<Bg, 64, 0, stream>>>(pools, W_mlp, b_mlp, out);
}

// Round 4
// 2369.571 us; speedup vs baseline: 1.0023x; 1.0023x over previous
//
#include <hip/hip_runtime.h>
#include <float.h>
#include <math.h>

#define Bg   8
#define NPGc 6250
#define Hh   4
#define Dd   128
#define Nn   50000
#define Ee   400000
#define HDd  512

__device__ __forceinline__ void atomicMaxF(float* addr, float val) {
    // ordered-int trick: works for mixed signs given IEEE-754 ordering
    if (val >= 0.0f) atomicMax((int*)addr, __float_as_int(val));
    else             atomicMin((unsigned int*)addr, __float_as_uint(val));
}

__global__ void init_kernel(float* m, float* denom, float* dout, float* din, float* pools) {
    int i = blockIdx.x * blockDim.x + threadIdx.x;
    if (i < Nn * Hh) { m[i] = -FLT_MAX; denom[i] = 0.0f; }
    if (i < Nn)      { dout[i] = 0.0f; din[i] = 0.0f; }
    if (i < Bg * 3 * Dd) pools[i] = -FLT_MAX;
}

__global__ void gather_kernel(const int* __restrict__ ids, const float* __restrict__ emb,
                              float* __restrict__ feat) {
    int i = blockIdx.x * blockDim.x + threadIdx.x;  // over N*32 float4s
    int n = i >> 5, c = i & 31;
    int id = ids[n];
    ((float4*)feat)[(size_t)n * 32 + c] = ((const float4*)emb)[(size_t)id * 32 + c];
}

// per-graph max over nodes for a [N,128] feature; blocks = (B, 50), 125 rows each
__global__ void maxpool_kernel(const float* __restrict__ x, float* __restrict__ pools, int col_off) {
    int b = blockIdx.x, chunk = blockIdx.y, d = threadIdx.x;
    int i0 = chunk * 125, i1 = i0 + 125;
    float mx = -FLT_MAX;
    for (int i = i0; i < i1; ++i)
        mx = fmaxf(mx, x[((size_t)(b * NPGc + i)) * Dd + d]);
    atomicMaxF(&pools[b * (3 * Dd) + col_off + d], mx);
}

// C[n,c] = leaky?( sum_k A[n,k]*scale(n) * W[k,c] + bias[c] )
// A:[n_rows,128], W:[128,WN], tile 64x64, 256 thr, 4x4 reg tile
__global__ __launch_bounds__(256) void gemm_kernel(
    const float* __restrict__ A, const float* __restrict__ W,
    const float* __restrict__ bias, float* __restrict__ C,
    int n_rows, int WN, const float* __restrict__ rowscale,
    int do_leak, float leak)
{
    __shared__ float As[64 * 132];   // padded stride 132
    __shared__ float Ws[64 * 64];    // one k-half at a time
    int row0 = blockIdx.x * 64;
    int col0 = blockIdx.y * 64;
    int tid  = threadIdx.x;

    // stage A tile: 64x128 = 8192 floats, 8 float4 per thread
    #pragma unroll
    for (int it = 0; it < 8; ++it) {
        int idx = (it * 256 + tid) * 4;
        int r = idx >> 7, c = idx & 127;
        int grow = row0 + r;
        float4 v = make_float4(0.f, 0.f, 0.f, 0.f);
        if (grow < n_rows) {
            v = *(const float4*)(A + (size_t)grow * 128 + c);
            if (rowscale) {
                float sc = 1.0f / sqrtf(fmaxf(rowscale[grow], 1.0f));
                v.x *= sc; v.y *= sc; v.z *= sc; v.w *= sc;
            }
        }
        *(float4*)(As + r * 132 + c) = v;
    }

    int tx = tid & 15, ty = tid >> 4;
    int r0 = ty * 4, c0 = tx * 4;
    float acc[4][4] = {};

    for (int kp = 0; kp < 2; ++kp) {
        __syncthreads();
        // stage W half: 64x64 = 4096 floats, 4 float4 per thread
        #pragma unroll
        for (int it = 0; it < 4; ++it) {
            int idx = (it * 256 + tid) * 4;
            int kk = idx >> 6, c = idx & 63;
            float4 v = *(const float4*)(W + (size_t)(kp * 64 + kk) * WN + col0 + c);
            *(float4*)(Ws + kk * 64 + c) = v;
        }
        __syncthreads();
        #pragma unroll 8
        for (int kk = 0; kk < 64; ++kk) {
            int k = kp * 64 + kk;
            float a[4];
            #pragma unroll
            for (int i = 0; i < 4; ++i) a[i] = As[(r0 + i) * 132 + k];
            float4 wv = *(const float4*)(Ws + kk * 64 + c0);
            float w[4] = {wv.x, wv.y, wv.z, wv.w};
            #pragma unroll
            for (int i = 0; i < 4; ++i)
                #pragma unroll
                for (int j = 0; j < 4; ++j)
                    acc[i][j] = fmaf(a[i], w[j], acc[i][j]);
        }
    }

    #pragma unroll
    for (int i = 0; i < 4; ++i) {
        int grow = row0 + r0 + i;
        if (grow >= n_rows) continue;
        float o[4];
        #pragma unroll
        for (int j = 0; j < 4; ++j) {
            float v = acc[i][j] + bias[col0 + c0 + j];
            if (do_leak) v = v >= 0.0f ? v : leak * v;
            o[j] = v;
        }
        *(float4*)(C + (size_t)grow * WN + col0 + c0) = *(float4*)o;
    }
}

// Pass A: one wave per edge; logits[e,h] = dot(leaky(hs[s]+hd[d],0.2), attn[h]); m = segmax
__global__ __launch_bounds__(256) void edge_logits_kernel(
    const float* __restrict__ hs, const float* __restrict__ hd,
    const int* __restrict__ src, const int* __restrict__ dst,
    const float* __restrict__ attn, float* __restrict__ logits, float* __restrict__ m)
{
    int w = (blockIdx.x * 256 + threadIdx.x) >> 6;
    int lane = threadIdx.x & 63;
    int s = src[w], d0 = dst[w];
    const float2* hsp = (const float2*)(hs + (size_t)s * HDd);
    const float2* hdp = (const float2*)(hd + (size_t)d0 * HDd);
    const float2* ap  = (const float2*)attn;
    #pragma unroll
    for (int h = 0; h < 4; ++h) {
        float2 a  = hsp[h * 64 + lane];
        float2 b  = hdp[h * 64 + lane];
        float2 at = ap[h * 64 + lane];
        float x0 = a.x + b.x; x0 = x0 >= 0.0f ? x0 : 0.2f * x0;
        float x1 = a.y + b.y; x1 = x1 >= 0.0f ? x1 : 0.2f * x1;
        float v = fmaf(x0, at.x, x1 * at.y);
        #pragma unroll
        for (int off = 32; off > 0; off >>= 1) v += __shfl_xor(v, off);
        if (lane == 0) {
            logits[(size_t)w * 4 + h] = v;
            atomicMaxF(&m[(size_t)d0 * 4 + h], v);
        }
    }
}

// Pass B: ex = exp(logit - m[dst]); denom[dst] += ex  (in-place over logits)
__global__ void edge_exp_kernel(const int* __restrict__ dst, float* __restrict__ logits,
                                const float* __restrict__ m, float* __restrict__ denom) {
    int i = blockIdx.x * blockDim.x + threadIdx.x;  // over E*4
    int e = i >> 2, h = i & 3;
    int d0 = dst[e];
    float ex = expf(logits[i] - m[(size_t)d0 * 4 + h]);
    logits[i] = ex;
    atomicAdd(&denom[(size_t)d0 * 4 + h], ex);
}

// Pass C: rst[dst] += hs[src] * alpha   (rst pre-initialized to x@W_res+b_res)
__global__ __launch_bounds__(256) void edge_aggregate_kernel(
    const float* __restrict__ hs, const float* __restrict__ ex, const float* __restrict__ denom,
    const int* __restrict__ src, const int* __restrict__ dst, float* __restrict__ rst)
{
    int w = (blockIdx.x * 256 + threadIdx.x) >> 6;
    int lane = threadIdx.x & 63;
    int s = src[w], d0 = dst[w];
    const float2* hsp = (const float2*)(hs + (size_t)s * HDd);
    float* rp = rst + (size_t)d0 * HDd;
    #pragma unroll
    for (int h = 0; h < 4; ++h) {
        float alpha = ex[(size_t)w * 4 + h] / denom[(size_t)d0 * 4 + h];
        float2 a = hsp[h * 64 + lane];
        atomicAdd(rp + h * 128 + 2 * lane,     a.x * alpha);
        atomicAdd(rp + h * 128 + 2 * lane + 1, a.y * alpha);
    }
}

// res[n,d] = mean_h leaky(rst[n,h,d], 0.01)
__global__ void head_mean_kernel(const float* __restrict__ rst, float* __restrict__ res) {
    int i = blockIdx.x * blockDim.x + threadIdx.x;  // N*128
    int n = i >> 7, d = i & 127;
    const float* r = rst + (size_t)n * HDd + d;
    float sum = 0.0f;
    #pragma unroll
    for (int h = 0; h < 4; ++h) {
        float v = r[h * 128];
        v = v >= 0.0f ? v : 0.01f * v;
        sum += v;
    }
    res[i] = 0.25f * sum;
}

__global__ void degree_kernel(const int* __restrict__ src, const int* __restrict__ dst,
                              float* __restrict__ dout, float* __restrict__ din) {
    int e = blockIdx.x * blockDim.x + threadIdx.x;
    if (e >= Ee) return;
    atomicAdd(&dout[src[e]], 1.0f);
    atomicAdd(&din[dst[e]], 1.0f);
}

// agg[dst] += res[src] * rsqrt(max(dout[src],1))
__global__ __launch_bounds__(256) void gc_agg_kernel(
    const float* __restrict__ res, const int* __restrict__ src, const int* __restrict__ dst,
    const float* __restrict__ dout, float* __restrict__ agg)
{
    int w = (blockIdx.x * 256 + threadIdx.x) >> 6;
    int lane = threadIdx.x & 63;
    int s = src[w], d0 = dst[w];
    float sc = 1.0f / sqrtf(fmaxf(dout[s], 1.0f));
    float2 a = ((const float2*)(res + (size_t)s * Dd))[lane];
    atomicAdd(agg + (size_t)d0 * Dd + 2 * lane,     a.x * sc);
    atomicAdd(agg + (size_t)d0 * Dd + 2 * lane + 1, a.y * sc);
}

// out[b] = relu(pools[b]) . W_mlp + b_mlp
__global__ void final_kernel(const float* __restrict__ pools, const float* __restrict__ W_mlp,
                             const float* __restrict__ b_mlp, float* __restrict__ out) {
    int b = blockIdx.x, lane = threadIdx.x;  // 64 threads
    float s = 0.0f;
    for (int j = lane; j < 3 * Dd; j += 64)
        s += fmaxf(pools[b * (3 * Dd) + j], 0.0f) * W_mlp[j];
    #pragma unroll
    for (int off = 32; off > 0; off >>= 1) s += __shfl_xor(s, off);
    if (lane == 0) out[b] = s + b_mlp[0];
}

extern "C" void kernel_launch(void* const* d_in, const int* in_sizes, int n_in,
                              void* d_out, int out_size, void* d_ws, size_t ws_size,
                              hipStream_t stream) {
    const int*   node_ids = (const int*)d_in[0];
    const int*   src      = (const int*)d_in[1];
    const int*   dst      = (const int*)d_in[2];
    const float* emb      = (const float*)d_in[3];
    const float* W_src    = (const float*)d_in[4];
    const float* b_src    = (const float*)d_in[5];
    const float* W_dst    = (const float*)d_in[6];
    const float* b_dst    = (const float*)d_in[7];
    const float* attn     = (const float*)d_in[8];
    const float* W_res    = (const float*)d_in[9];
    const float* b_res    = (const float*)d_in[10];
    const float* W_gc     = (const float*)d_in[11];
    const float* b_gc     = (const float*)d_in[12];
    const float* W_mlp    = (const float*)d_in[13];
    const float* b_mlp    = (const float*)d_in[14];
    float* out = (float*)d_out;

    float* ws = (float*)d_ws;
    size_t off = 0;
    float* feat   = ws + off; off += (size_t)Nn * Dd;    // reused as res later
    float* hs     = ws + off; off += (size_t)Nn * HDd;   // reused as agg + res2 later
    float* hd     = ws + off; off += (size_t)Nn * HDd;   // reused as rst later
    float* logits = ws + off; off += (size_t)Ee * Hh;    // reused as ex in-place
    float* m      = ws + off; off += (size_t)Nn * Hh;
    float* denom  = ws + off; off += (size_t)Nn * Hh;
    float* doutd  = ws + off; off += Nn;
    float* dind   = ws + off; off += Nn;
    float* pools  = ws + off; off += Bg * 3 * Dd;

    float* rst  = hd;                         // hd dead after edge_logits
    float* res  = feat;                       // feat dead after W_res GEMM
    float* agg  = hs;                         // hs dead after edge_aggregate
    float* res2 = hs + (size_t)Nn * Dd;

    init_kernel<<<(Nn * Hh + 255) / 256, 256, 0, stream>>>(m, denom, doutd, dind, pools);
    gather_kernel<<<(Nn * 32) / 256, 256, 0, stream>>>(node_ids, emb, feat);
    maxpool_kernel<<<dim3(Bg, 50), Dd, 0, stream>>>(feat, pools, 0);

    gemm_kernel<<<dim3(782, 8), 256, 0, stream>>>(feat, W_src, b_src, hs, Nn, HDd, nullptr, 0, 0.0f);
    gemm_kernel<<<dim3(782, 8), 256, 0, stream>>>(feat, W_dst, b_dst, hd, Nn, HDd, nullptr, 0, 0.0f);

    edge_logits_kernel<<<Ee / 4, 256, 0, stream>>>(hs, hd, src, dst, attn, logits, m);
    edge_exp_kernel<<<(Ee * Hh) / 256, 256, 0, stream>>>(dst, logits, m, denom);

    gemm_kernel<<<dim3(782, 8), 256, 0, stream>>>(feat, W_res, b_res, rst, Nn, HDd, nullptr, 0, 0.0f);
    edge_aggregate_kernel<<<Ee / 4, 256, 0, stream>>>(hs, logits, denom, src, dst, rst);

    head_mean_kernel<<<(Nn * Dd) / 256, 256, 0, stream>>>(rst, res);
    maxpool_kernel<<<dim3(Bg, 50), Dd, 0, stream>>>(res, pools, Dd);

    degree_kernel<<<(Ee + 255) / 256, 256, 0, stream>>>(src, dst, doutd, dind);
    hipMemsetAsync(agg, 0, (size_t)Nn * Dd * sizeof(float), stream);
    gc_agg_kernel<<<Ee / 4, 256, 0, stream>>>(res, src, dst, doutd, agg);
    gemm_kernel<<<dim3(782, 2), 256, 0, stream>>>(agg, W_gc, b_gc, res2, Nn, Dd, dind, 1, 0.01f);
    maxpool_kernel<<<dim3(Bg, 50), Dd, 0, stream>>>(res2, pools, 2 * Dd);

    final_kernel<<<Bg, 64, 0, stream>>>(pools, W_mlp, b_mlp, out);
}